// Round 5
// baseline (266.696 us; speedup 1.0000x reference)
//
#include <hip/hip_runtime.h>

// ---------------------------------------------------------------------------
// SimpleBiquadEQ: 10-band peaking-EQ cascade (IIR) over [32,2,262144] fp32.
// Exact chunk-parallel state-passing scan. Round 5 (= R4 + compile fix):
//  - scan fused into ONE kernel; combine matrices read via wave-uniform
//    pointers -> scalar loads -> SGPR-operand FMAs (no per-lane LDS reads);
//    all matrix math exploits block-lower-triangular structure (220/400 nz).
//  - passes: x preloaded to registers (single vmcnt wait), x-history via
//    __shfl_up; pass_zero has no LDS; pass_out keeps R3's proven XOR-swizzle
//    LDS store staging (WRITE_SIZE was exact 65 MB, ~0 conflicts).
// ---------------------------------------------------------------------------

#define B_   32
#define S_   262144
#define NB   10
#define SEQ  64
#define LCH  64            // samples per chunk
#define PCH  4096          // chunks per sequence
#define GG   8             // chunks per scan group
#define GRP  512           // groups per sequence
#define NPOW 10            // slot0=A^64 ; slot1..9 = A^2^9 .. A^2^17 (transposed)

// ws layout (floats): coef[32][50] @0 ; powT[32][10][400] @1600 ;
//                     t[64][4096][20] @129600 -> total 5,372,480 f = 21.5 MB
#define WS_POW 1600
#define WS_T   129600

// ---------------------------------------------------------------------------
// triangular matvec-accumulate: acc += M * v, M column-major (M[c*20+r]),
// block-lower-triangular: column c has rows r >= (c & ~1).
// M is wave-uniform -> compiler emits s_load + SGPR-operand v_fma.
// ---------------------------------------------------------------------------
__device__ __forceinline__ void trimv_acc(float* __restrict__ acc,
                                          const float* __restrict__ M,
                                          const float* __restrict__ v) {
  #pragma unroll
  for (int c = 0; c < 20; ++c) {
    const int rlo = c & ~1;
    const float vc = v[c];
    #pragma unroll
    for (int r = rlo; r < 20; ++r)
      acc[r] = fmaf(M[c * 20 + r], vc, acc[r]);
  }
}

// ===========================================================================
// setup: coefficients + transposed triangular matrix powers
// ===========================================================================
__global__ __launch_bounds__(256) void setup_kernel(
    const float* __restrict__ freqs, const float* __restrict__ gains,
    const float* __restrict__ qs, float* __restrict__ coef,
    float* __restrict__ powT) {
  __shared__ float bufA[400], bufB[400];
  __shared__ float cfs[NB * 5];
  const int b = blockIdx.x, tid = threadIdx.x;
  for (int e = tid; e < 400; e += 256) bufA[e] = 0.0f;
  if (tid < NB) {
    int idx = b * NB + tid;
    float f = freqs[idx], g = gains[idx], Q = qs[idx];
    float w0 = 6.28318530717958648f * f / 44100.0f;
    float sw = sinf(w0), cw = cosf(w0);
    float alpha = sw / (2.0f * Q);
    float A = expf(g * 0.05756462732485114f);   // 10^(g/40)
    float aA = alpha * A, adA = alpha / A;
    float inv = 1.0f / (1.0f + adA);
    float c0 = (1.0f + aA) * inv;
    float c1 = -2.0f * cw * inv;
    float c2 = (1.0f - aA) * inv;
    float c3 = 2.0f * cw * inv;      // -a1
    float c4 = -(1.0f - adA) * inv;  // -a2
    cfs[tid*5+0] = c0; cfs[tid*5+1] = c1; cfs[tid*5+2] = c2;
    cfs[tid*5+3] = c3; cfs[tid*5+4] = c4;
    float* o = coef + idx * 5;
    o[0] = c0; o[1] = c1; o[2] = c2; o[3] = c3; o[4] = c4;
  }
  __syncthreads();
  if (tid < 20) {          // build A; thread owns column tid
    int c = tid;
    float rp = 0.0f;
    for (int k = 0; k < NB; k++) {
      float b0 = cfs[k*5+0], b1 = cfs[k*5+1], b2 = cfs[k*5+2];
      float na1 = cfs[k*5+3], na2 = cfs[k*5+4];
      float val = (k > 0) ? b0 * rp : 0.0f;
      if (k > 0) {
        if (c == 2*k-2) val += b1;
        if (c == 2*k-1) val += b2;
      }
      if (c == 2*k)   val += na1;
      if (c == 2*k+1) val += na2;
      bufA[2*k*20 + c] = val;
      rp = val;
      if (c == 2*k) bufA[(2*k+1)*20 + c] = 1.0f;
    }
  }
  __syncthreads();
  float* cur = bufA;
  float* nxt = bufB;
  float* pw = powT + (size_t)b * NPOW * 400;
  for (int j = 1; j <= 17; j++) {    // cur becomes A^(2^j)
    for (int e = tid; e < 400; e += 256) {
      int r = e / 20, c = e % 20;
      float acc = 0.0f;
      if ((c >> 1) <= (r >> 1)) {
        const int klo = c & ~1, khi = r | 1;
        for (int k = klo; k <= khi; ++k)
          acc = fmaf(cur[r*20+k], cur[k*20+c], acc);
      }
      nxt[e] = acc;
    }
    __syncthreads();
    { float* t_ = cur; cur = nxt; nxt = t_; }
    int slot = -1;
    if (j == 6) slot = 0;            // A^64
    else if (j >= 9) slot = j - 8;   // A^512 .. A^131072
    if (slot >= 0) {
      for (int e = tid; e < 400; e += 256) {
        int r = e / 20, c = e % 20;
        if ((c >> 1) <= (r >> 1))
          pw[slot*400 + c*20 + r] = cur[r*20+c];   // transposed (col-major)
      }
    }
  }
}

// ===========================================================================
// pass 1: zero-state chunk run -> t. wg=256 (4 waves), no LDS.
// ===========================================================================
__global__ __launch_bounds__(256) void pass_zero(
    const float* __restrict__ x, const float* __restrict__ coef,
    float* __restrict__ t) {
  const int seq = blockIdx.y, b = seq >> 1;
  const int chunk = blockIdx.x * 256 + threadIdx.x;
  const int lane = threadIdx.x & 63;
  const float* cf = coef + b * NB * 5;         // uniform -> SGPRs
  float b0[NB], b1[NB], b2[NB], na1[NB], na2[NB];
  #pragma unroll
  for (int k = 0; k < NB; k++) {
    b0[k] = cf[k*5+0]; b1[k] = cf[k*5+1]; b2[k] = cf[k*5+2];
    na1[k] = cf[k*5+3]; na2[k] = cf[k*5+4];
  }
  const float* xs = x + (size_t)seq * S_ + (size_t)chunk * LCH;
  const float4* xv = (const float4*)xs;
  float4 xr[16];
  #pragma unroll
  for (int i = 0; i < 16; i++) xr[i] = xv[i];  // all loads in flight at once
  float up_z = __shfl_up(xr[15].z, 1, 64);     // prev chunk sample 62
  float up_w = __shfl_up(xr[15].w, 1, 64);     // prev chunk sample 63
  float x1, x2;
  if (lane == 0) {
    x1 = 0.0f; x2 = 0.0f;
    if (chunk > 0) { x1 = xs[-1]; x2 = xs[-2]; }
  } else { x1 = up_w; x2 = up_z; }
  float p[NB], q_[NB];
  #pragma unroll
  for (int k = 0; k < NB; k++) { p[k] = 0.0f; q_[k] = 0.0f; }
  #pragma unroll
  for (int qq = 0; qq < 16; qq++) {
    float xin[4] = {xr[qq].x, xr[qq].y, xr[qq].z, xr[qq].w};
    #pragma unroll
    for (int j = 0; j < 4; j++) {
      float u = xin[j], u1 = x1, u2 = x2;
      x2 = x1; x1 = xin[j];
      #pragma unroll
      for (int k = 0; k < NB; k++) {
        float v = fmaf(b0[k], u,
                  fmaf(b1[k], u1,
                  fmaf(b2[k], u2,
                  fmaf(na1[k], p[k], na2[k] * q_[k]))));
        u1 = p[k]; u2 = q_[k];
        q_[k] = p[k]; p[k] = v;
        u = v;
      }
    }
  }
  float4* td = (float4*)(t + ((size_t)seq * PCH + chunk) * 20);
  #pragma unroll
  for (int i = 0; i < 5; i++)
    td[i] = make_float4(p[2*i], q_[2*i], p[2*i+1], q_[2*i+1]);
}

// ===========================================================================
// scan: one kernel. 64 wgs x 512 threads; thread = group of 8 chunks.
// Horner (A^64) -> 9-step KS over 512 group totals -> rewalk, in-place on t.
// Matrices via uniform global pointers (SGPR path), triangular only.
// ===========================================================================
__device__ __forceinline__ void h_write(float4* __restrict__ h4, int j,
                                        const float* __restrict__ s) {
  const int m5 = j % 5;                        // rotate f4 slots: break stride
  #pragma unroll
  for (int k = 0; k < 5; k++) {
    int sl = k + m5; if (sl >= 5) sl -= 5;
    h4[j*5 + sl] = make_float4(s[4*k], s[4*k+1], s[4*k+2], s[4*k+3]);
  }
}
__device__ __forceinline__ void h_read(const float4* __restrict__ h4, int j,
                                       float* __restrict__ s) {
  const int m5 = j % 5;
  #pragma unroll
  for (int k = 0; k < 5; k++) {
    int sl = k + m5; if (sl >= 5) sl -= 5;
    float4 a = h4[j*5 + sl];
    s[4*k] = a.x; s[4*k+1] = a.y; s[4*k+2] = a.z; s[4*k+3] = a.w;
  }
}

__global__ __launch_bounds__(512) void scan_kernel(
    float* __restrict__ t, const float* __restrict__ powT) {
  __shared__ float4 h4[GRP * 5];               // 40 KB
  const int seq = blockIdx.x, b = seq >> 1, i = threadIdx.x;
  const float* M = powT + (size_t)b * NPOW * 400;   // slot0 = A^64 (col-major)
  float* tb = t + (size_t)seq * PCH * 20;
  float s[20];
  #pragma unroll
  for (int r = 0; r < 20; r++) s[r] = 0.0f;
  // ---- Horner over my 8 chunks: s <- A^64 s + t_j ----
  for (int j = 0; j < GG; j++) {
    float ns[20];
    const float4* tv = (const float4*)(tb + ((size_t)i * GG + j) * 20);
    #pragma unroll
    for (int k = 0; k < 5; k++) {
      float4 a = tv[k];
      ns[4*k] = a.x; ns[4*k+1] = a.y; ns[4*k+2] = a.z; ns[4*k+3] = a.w;
    }
    trimv_acc(ns, M, s);
    #pragma unroll
    for (int r = 0; r < 20; r++) s[r] = ns[r];
  }
  h_write(h4, i, s);
  // ---- Kogge-Stone over 512 totals; step st uses A^(512*2^st) ----
  for (int st = 0; st < 9; st++) {
    const int d = 1 << st;
    const float* K = M + (size_t)(1 + st) * 400;
    __syncthreads();                 // h stable (writes from prev step done)
    float nb[20];
    const bool en = (i >= d);
    if (en) h_read(h4, i - d, nb);
    __syncthreads();                 // all reads done before republish
    if (en) {
      trimv_acc(s, K, nb);
      h_write(h4, i, s);
    }
  }
  __syncthreads();
  // ---- exclusive prefix -> rewalk my 8 chunks, write true states back ----
  float P[20];
  if (i > 0) {
    h_read(h4, i - 1, P);
  } else {
    for (int r = 0; r < 20; r++) P[r] = 0.0f;
  }
  for (int j = 0; j < GG; j++) {
    float ns[20];
    float* tp = tb + ((size_t)i * GG + j) * 20;
    const float4* tv = (const float4*)tp;
    #pragma unroll
    for (int k = 0; k < 5; k++) {
      float4 a = tv[k];
      ns[4*k] = a.x; ns[4*k+1] = a.y; ns[4*k+2] = a.z; ns[4*k+3] = a.w;
    }
    trimv_acc(ns, M, P);
    #pragma unroll
    for (int r = 0; r < 20; r++) P[r] = ns[r];
    float4* tw = (float4*)tp;
    #pragma unroll
    for (int k = 0; k < 5; k++)
      tw[k] = make_float4(P[4*k], P[4*k+1], P[4*k+2], P[4*k+3]);
  }
}

// ===========================================================================
// pass 2: exact run from scanned state; register x, LDS-staged stores (R3).
// ===========================================================================
__global__ __launch_bounds__(64) void pass_out(
    const float* __restrict__ x, const float* __restrict__ coef,
    const float* __restrict__ t, float* __restrict__ out) {
  __shared__ float4 lds4[1024];                // 16 KB y-staging
  const int seq = blockIdx.y, b = seq >> 1;
  const int lane = threadIdx.x;
  const int chunk = blockIdx.x * 64 + lane;
  const float* cf = coef + b * NB * 5;
  float b0[NB], b1[NB], b2[NB], na1[NB], na2[NB];
  #pragma unroll
  for (int k = 0; k < NB; k++) {
    b0[k] = cf[k*5+0]; b1[k] = cf[k*5+1]; b2[k] = cf[k*5+2];
    na1[k] = cf[k*5+3]; na2[k] = cf[k*5+4];
  }
  const size_t span0 = (size_t)seq * S_ + (size_t)blockIdx.x * 64 * LCH;
  const float* xs = x + (size_t)seq * S_ + (size_t)chunk * LCH;
  const float4* xv = (const float4*)xs;
  float4 xr[16];
  #pragma unroll
  for (int i = 0; i < 16; i++) xr[i] = xv[i];
  float up_z = __shfl_up(xr[15].z, 1, 64);
  float up_w = __shfl_up(xr[15].w, 1, 64);
  float x1, x2;
  if (lane == 0) {
    x1 = 0.0f; x2 = 0.0f;
    if (chunk > 0) { x1 = xs[-1]; x2 = xs[-2]; }
  } else { x1 = up_w; x2 = up_z; }
  float p[NB], q_[NB];
  if (chunk > 0) {
    const float4* sv = (const float4*)(t + ((size_t)seq * PCH + chunk - 1) * 20);
    #pragma unroll
    for (int i = 0; i < 5; i++) {
      float4 a = sv[i];
      p[2*i] = a.x; q_[2*i] = a.y; p[2*i+1] = a.z; q_[2*i+1] = a.w;
    }
  } else {
    #pragma unroll
    for (int k = 0; k < NB; k++) { p[k] = 0.0f; q_[k] = 0.0f; }
  }
  #pragma unroll
  for (int qq = 0; qq < 16; qq++) {
    float xin[4] = {xr[qq].x, xr[qq].y, xr[qq].z, xr[qq].w};
    float o[4];
    #pragma unroll
    for (int j = 0; j < 4; j++) {
      float u = xin[j], u1 = x1, u2 = x2;
      x2 = x1; x1 = xin[j];
      #pragma unroll
      for (int k = 0; k < NB; k++) {
        float v = fmaf(b0[k], u,
                  fmaf(b1[k], u1,
                  fmaf(b2[k], u2,
                  fmaf(na1[k], p[k], na2[k] * q_[k]))));
        u1 = p[k]; u2 = q_[k];
        q_[k] = p[k]; p[k] = v;
        u = v;
      }
      o[j] = u;
    }
    lds4[lane*16 + (qq ^ (lane & 15))] = make_float4(o[0], o[1], o[2], o[3]);
  }
  __syncthreads();
  float4* gy = (float4*)(out + span0);
  #pragma unroll 4
  for (int it = 0; it < 16; it++) {
    int f = it * 64 + lane;
    int c = f >> 4, q = f & 15;
    gy[f] = lds4[c*16 + (q ^ (c & 15))];
  }
}

// ===========================================================================
extern "C" void kernel_launch(void* const* d_in, const int* in_sizes, int n_in,
                              void* d_out, int out_size, void* d_ws, size_t ws_size,
                              hipStream_t stream) {
  const float* audio = (const float*)d_in[0];
  const float* freqs = (const float*)d_in[1];
  const float* gains = (const float*)d_in[2];
  const float* qs    = (const float*)d_in[3];
  float* out  = (float*)d_out;
  float* ws   = (float*)d_ws;
  float* coef = ws;
  float* powT = ws + WS_POW;
  float* t    = ws + WS_T;

  hipLaunchKernelGGL(setup_kernel, dim3(B_), dim3(256), 0, stream,
                     freqs, gains, qs, coef, powT);
  hipLaunchKernelGGL(pass_zero, dim3(PCH / 256, SEQ), dim3(256), 0, stream,
                     audio, coef, t);
  hipLaunchKernelGGL(scan_kernel, dim3(SEQ), dim3(512), 0, stream, t, powT);
  hipLaunchKernelGGL(pass_out, dim3(PCH / 64, SEQ), dim3(64), 0, stream,
                     audio, coef, t, out);
}